// Round 1
// baseline (398.773 us; speedup 1.0000x reference)
//
#include <hip/hip_runtime.h>
#include <cmath>

// ---------------------------------------------------------------------------
// Fused 3D SSIM, separable Gaussian 11-tap, VALID. fp32 (2,1,192,192,192).
// z-streaming slab, x-paired threads + packed-fp32 (v_pk_fma_f32) math:
//   tile 32(x) x 16(y), 256 threads, thread owns x-pair; acc[5][11] float2.
//
// Round-8 change (occupancy-cap analysis): VGPR_Count=84 is arch-only; the
// 110-float acc state lives in the unified VGPR/AGPR file -> true alloc ~170
// -> HW grants 2 waves/SIMD (8 waves/CU, 25% cap; measured 26%). Kernel is
// latency-bound at that ceiling. Since the cap can't move (acc=110 floats,
// 128-reg cliff infeasible per r6), spend the FREE headroom up to 256 regs:
//   * tws double-buffered (33.3 KB, affordable at 2 blocks/CU residency)
//     -> ONE __syncthreads per plane (was 2; 34 barriers instead of 68).
//   * 1-plane-deep register prefetch of W inputs (48 VGPRs), loads issued
//     right AFTER the barrier so the implicit vmcnt(0) drain at
//     __syncthreads never waits on them; latency hides under H+D+SSIM.
//   * launch_bounds(256,2): regalloc cap 256 (occupancy unchanged).
//
// DO NOT: tighten launch bounds to (256,3+) with the prefetch in place —
//         the live set is ~220 regs; a 170 cap spills acc (r6: 4x regression)
// DO NOT: put the prefetch loads BEFORE the __syncthreads — its implicit
//         s_waitcnt vmcnt(0) would serialize on them.
// ---------------------------------------------------------------------------

#define WSZ 11
#define DIN 192
#define DOUTS 182
#define TH 16              // tile height (output rows, y)
#define TWD 32             // tile width  (output cols, x)
#define IHR 26             // input rows per plane tile (TH + 10)
#define ZCH 24             // output planes per chunk
#define ZIN 34             // input planes per chunk (ZCH + 10)
#define NTX 6              // x tiles (6*32 = 192)
#define NTY 12             // y tiles (12*16 = 192)
#define ZC 8               // z-chunks (8*24 = 192)
#define NBLK (NTX*NTY*2*ZC)  // 1152
static constexpr double SOUT = 2.0 * 182.0 * 182.0 * 182.0;  // 12,057,136

typedef float v2f __attribute__((ext_vector_type(2)));

struct G11 { float g[WSZ]; };

__device__ __forceinline__ v2f pkfma(float g, v2f v, v2f a) {
    v2f gg = {g, g};
    return __builtin_elementwise_fma(gg, v, a);
}

__device__ __forceinline__ unsigned int enc_f(float f) {
    unsigned int u = __float_as_uint(f);
    return (u & 0x80000000u) ? ~u : (u | 0x80000000u);
}
__device__ __forceinline__ float dec_f(unsigned int u) {
    return (u & 0x80000000u) ? __uint_as_float(u & 0x7FFFFFFFu) : __uint_as_float(~u);
}

// ---------------------------------------------------------------------------
__global__ void k_init(unsigned int* mm, double* sum) {
    sum[0] = 0.0;
    mm[0] = 0u;           // encoded -inf (max accumulator)
    mm[1] = 0xFFFFFFFFu;  // encoded +inf (min accumulator)
}

// ---------------------------------------------------------------------------
__global__ __launch_bounds__(256) void k_minmax(const float4* __restrict__ img1,
                                                int n4, unsigned int* mm) {
    float mx = -1e30f, mn = 1e30f;
    for (int i = blockIdx.x * blockDim.x + threadIdx.x; i < n4;
         i += gridDim.x * blockDim.x) {
        float4 v = img1[i];
        mx = fmaxf(mx, fmaxf(fmaxf(v.x, v.y), fmaxf(v.z, v.w)));
        mn = fminf(mn, fminf(fminf(v.x, v.y), fminf(v.z, v.w)));
    }
    #pragma unroll
    for (int o = 32; o; o >>= 1) {
        mx = fmaxf(mx, __shfl_down(mx, o));
        mn = fminf(mn, __shfl_down(mn, o));
    }
    __shared__ float smx[4], smn[4];
    int lane = threadIdx.x & 63, wv = threadIdx.x >> 6;
    if (lane == 0) { smx[wv] = mx; smn[wv] = mn; }
    __syncthreads();
    if (threadIdx.x == 0) {
        #pragma unroll
        for (int i = 1; i < 4; i++) { mx = fmaxf(mx, smx[i]); mn = fminf(mn, smn[i]); }
        atomicMax(&mm[0], enc_f(mx));
        atomicMin(&mm[1], enc_f(mn));
    }
}

// ---------------------------------------------------------------------------
// W-phase x-conv for one (row h, x-pair xo) item from prefetched registers.
// Lane-pair of every v2f is (img1, img2); o indexes the 2 x-outputs.
__device__ __forceinline__ void wconv(const float2 f1[6], const float2 f2[6],
                                      const G11& gw, int h, int xo,
                                      float (*tw)[IHR][TWD]) {
    v2f p[12];
    #pragma unroll
    for (int q = 0; q < 6; q++) {
        p[2*q]   = (v2f){f1[q].x, f2[q].x};
        p[2*q+1] = (v2f){f1[q].y, f2[q].y};
    }
    v2f amu[2] = {{0.f,0.f},{0.f,0.f}};      // (mu1, mu2) per output
    v2f asq[2] = {{0.f,0.f},{0.f,0.f}};      // (E11, E22) per output
    float a12[2] = {0.f, 0.f};               // E12 per output
    #pragma unroll
    for (int k = 0; k < WSZ; k++) {
        float g = gw.g[k];
        #pragma unroll
        for (int o = 0; o < 2; o++) {
            v2f e = p[k + o];
            v2f t = (v2f){g, g} * e;         // pk_mul
            amu[o] += t;                     // pk_add
            asq[o] = __builtin_elementwise_fma(t, e, asq[o]);  // pk_fma
            a12[o] = fmaf(t.x, e.y, a12[o]); // cross term
        }
    }
    *(v2f*)&tw[0][h][xo] = (v2f){amu[0].x, amu[1].x};
    *(v2f*)&tw[1][h][xo] = (v2f){amu[0].y, amu[1].y};
    *(v2f*)&tw[2][h][xo] = (v2f){asq[0].x, asq[1].x};
    *(v2f*)&tw[3][h][xo] = (v2f){asq[0].y, asq[1].y};
    *(v2f*)&tw[4][h][xo] = (v2f){a12[0],   a12[1]};
}

// ---------------------------------------------------------------------------
// launch_bounds(256, 2): regalloc cap 256; occupancy is 2 waves/SIMD anyway.
__global__ __launch_bounds__(256, 2) void k_ssim(const float* __restrict__ img1,
                                                 const float* __restrict__ img2,
                                                 const unsigned int* __restrict__ mm,
                                                 double* __restrict__ sum, G11 gw) {
    __shared__ float tws[2][5][IHR][TWD];  // double-buffered W-conv plane, 33.3 KB
    __shared__ float sred[4];

    int b   = blockIdx.x;
    int twi = b % NTX;
    int thi = (b / NTX) % NTY;
    int rest = b / (NTX * NTY);
    int tc  = rest % ZC;
    int n   = rest / ZC;                 // batch 0..1
    int ow0 = twi * TWD, oh0 = thi * TH, od0 = tc * ZCH;
    int tid = threadIdx.x;
    int y = tid >> 4, xg = tid & 15;     // thread owns outputs (y, 2xg), (y, 2xg+1)
    int x0 = 2 * xg;

    // SSIM constants (L from img1 min/max, computed by k_minmax)
    float maxv = dec_f(mm[0]);
    float minv = dec_f(mm[1]);
    float max_val = (maxv > 128.0f) ? 255.0f : 1.0f;
    float min_val = (minv < -0.5f) ? -1.0f : 0.0f;
    float L  = max_val - min_val;
    float C1 = 0.01f * L; C1 *= C1;
    float C2 = 0.03f * L; C2 *= C2;

    bool vy  = (oh0 + y < DOUTS);
    bool vx0 = vy && (ow0 + x0 < DOUTS);
    bool vx1 = vy && (ow0 + x0 + 1 < DOUTS);

    // W-item geometry: item0 = row y (all threads), item1 = row y+16 (tid<160).
    // Clamped rows/cols feed only masked outputs; loads stay in-bounds.
    int hr0 = min(oh0 + y, DIN - 1);
    int hr1 = min(oh0 + y + 16, DIN - 1);
    int s   = min(ow0 + x0, DIN - 12);   // even -> float2 loads 8B-aligned
    bool has1 = (tid < 160);             // y+16 < IHR

    const size_t nbase = (size_t)n * DIN * DIN * DIN;
    const float* pa1 = img1 + nbase + (size_t)hr0 * DIN + s;
    const float* pa2 = img2 + nbase + (size_t)hr0 * DIN + s;
    const float* pb1 = img1 + nbase + (size_t)hr1 * DIN + s;
    const float* pb2 = img2 + nbase + (size_t)hr1 * DIN + s;

    // Prefetch registers for one input plane (2 items x 12 float2 = 48 VGPR)
    float2 f1a[6], f2a[6], f1b[6], f2b[6];

#define LOAD_PLANE(ZOFF)                                                \
    {   const float2* q1 = (const float2*)(pa1 + (ZOFF));               \
        const float2* q2 = (const float2*)(pa2 + (ZOFF));               \
        _Pragma("unroll")                                               \
        for (int q = 0; q < 6; q++) { f1a[q] = q1[q]; f2a[q] = q2[q]; } \
        if (has1) {                                                     \
            const float2* r1 = (const float2*)(pb1 + (ZOFF));           \
            const float2* r2 = (const float2*)(pb2 + (ZOFF));           \
            _Pragma("unroll")                                           \
            for (int q = 0; q < 6; q++) { f1b[q] = r1[q]; f2b[q] = r2[q]; } \
        } }

    // D-conv packed shift pipeline: acc[c][j] covers output zo = zi - j.
    v2f acc[5][WSZ];
    float local = 0.f;

    // prologue: plane 0
    {
        size_t zoff = (size_t)min(od0, DIN - 1) * (size_t)(DIN * DIN);
        LOAD_PLANE(zoff);
    }

    for (int zi = 0; zi < ZIN; zi++) {
        float (*tw)[IHR][TWD] = tws[zi & 1];

        // ---- W phase: compute from prefetched regs, write tws[zi&1] ----
        wconv(f1a, f2a, gw, y, x0, tw);
        if (has1) wconv(f1b, f2b, gw, y + 16, x0, tw);

        __syncthreads();   // W writes visible before H reads (only barrier/plane)

        // ---- issue next plane's loads; latency hides under H + D + SSIM ----
        if (zi + 1 < ZIN) {
            size_t zoff = (size_t)min(od0 + zi + 1, DIN - 1) * (size_t)(DIN * DIN);
            LOAD_PLANE(zoff);
        }

        // ---- H phase: packed over the x-pair, ds_read_b64 per (c,k) ----
        v2f m[5];
        #pragma unroll
        for (int c = 0; c < 5; c++) {
            v2f a = {0.f, 0.f};
            #pragma unroll
            for (int k = 0; k < WSZ; k++) {
                v2f vv = *(const v2f*)&tw[c][y + k][x0];
                a = pkfma(gw.g[k], vv, a);
            }
            m[c] = a;
        }
        // NOTE: no second barrier — tws is double-buffered; W(zi+2)'s reuse of
        // this buffer is ordered after every wave's H(zi) by the barrier at zi+1.

        // ---- D shift-FMA (packed): acc[j] = g[j]*m + acc[j-1] ----
        #pragma unroll
        for (int c = 0; c < 5; c++) {
            #pragma unroll
            for (int j = WSZ - 1; j >= 1; j--)
                acc[c][j] = pkfma(gw.g[j], m[c], acc[c][j-1]);
            acc[c][0] = (v2f){gw.g[0], gw.g[0]} * m[c];
        }

        // ---- SSIM for completed output plane zo = zi - 10 ----
        if (zi >= WSZ - 1) {
            int zo = od0 + zi - (WSZ - 1);
            if (zo < DOUTS) {            // uniform branch
                v2f mu1 = acc[0][10], mu2 = acc[1][10];
                v2f mu1s = mu1 * mu1, mu2s = mu2 * mu2, mu12 = mu1 * mu2;
                v2f s1  = acc[2][10] - mu1s;
                v2f s2  = acc[3][10] - mu2s;
                v2f s12 = acc[4][10] - mu12;
                v2f c2v = {C2, C2};
                v2f v1  = (v2f){2.f,2.f} * s12 + c2v;
                v2f v2  = s1 + s2 + c2v;
                v2f c1v = {C1, C1};
                v2f num = ((v2f){2.f,2.f} * mu12 + c1v) * v1;
                v2f den = (mu1s + mu2s + c1v) * v2;
                v2f ss  = num / den;
                if (vx0) local += ss.x;
                if (vx1) local += ss.y;
            }
        }
    }
#undef LOAD_PLANE

    // ---- block reduction -> one f64 atomic ----
    #pragma unroll
    for (int o = 32; o; o >>= 1) local += __shfl_down(local, o);
    if ((tid & 63) == 0) sred[tid >> 6] = local;
    __syncthreads();
    if (tid == 0)
        atomicAdd(sum, (double)(sred[0] + sred[1] + sred[2] + sred[3]));
}

// ---------------------------------------------------------------------------
__global__ void k_final(const double* __restrict__ sum, float* __restrict__ out) {
    out[0] = (float)(sum[0] / SOUT);
}

// ---------------------------------------------------------------------------
extern "C" void kernel_launch(void* const* d_in, const int* in_sizes, int n_in,
                              void* d_out, int out_size, void* d_ws, size_t ws_size,
                              hipStream_t stream) {
    const float* img1 = (const float*)d_in[0];
    const float* img2 = (const float*)d_in[1];
    float* out = (float*)d_out;

    char* ws = (char*)d_ws;
    double*       sum = (double*)ws;              // 8 B
    unsigned int* mm  = (unsigned int*)(ws + 8);  // 8 B

    // Gaussian weights: f64 compute, normalize, cast to f32 (matches ref).
    G11 g;
    {
        double gd[WSZ], s = 0.0;
        for (int i = 0; i < WSZ; i++) {
            double d = (double)(i - WSZ / 2);
            gd[i] = std::exp(-(d * d) / (2.0 * 1.5 * 1.5));
            s += gd[i];
        }
        for (int i = 0; i < WSZ; i++) g.g[i] = (float)(gd[i] / s);
    }

    int n_img = 2 * DIN * DIN * DIN;  // 14,155,776

    k_init<<<1, 1, 0, stream>>>(mm, sum);
    k_minmax<<<2048, 256, 0, stream>>>((const float4*)img1, n_img / 4, mm);
    k_ssim<<<NBLK, 256, 0, stream>>>(img1, img2, mm, sum, g);
    k_final<<<1, 1, 0, stream>>>(sum, out);
}

// Round 2
// 366.013 us; speedup vs baseline: 1.0895x; 1.0895x over previous
//
#include <hip/hip_runtime.h>
#include <cmath>

// ---------------------------------------------------------------------------
// Fused 3D SSIM, separable Gaussian 11-tap, VALID. fp32 (2,1,192,192,192).
// z-streaming slab. Round-9 restructure: ONE OUTPUT COLUMN PER THREAD,
// channel-packed math, targeting the 128-reg / 4-waves-per-SIMD tier.
//
// Occupancy ladder (measured r0 vs r1): alloc<=170 -> 3 waves/SIMD (r0,
// 25.8% time-avg, 218 us); alloc>170 -> 2 waves/SIMD (r1, 18.8%, 260 us).
// Kernel is latency-bound, so waves/SIMD is THE lever. The old x-pair
// structure pins acc state at 110 floats/thread (55/output), making the
// 128-reg tier unreachable (r6: forcing it spills). This version:
//   * thread owns 1 output column -> acc = 55 floats (accMu/accE v2f + acc12)
//   * packed math preserved by packing CHANNELS (mu1,mu2)/(E11,E22) --
//     the W phase already produces exactly those v2f pairs
//   * 512-thread blocks (tile 32x16 unchanged), __launch_bounds__(512,4)
//     -> reg cap 128 -> 4 waves/SIMD = 16 waves/CU (2 blocks x 8 waves)
//   * LDS channel-interleaved, stride 34 (bank-conflict-free, verified for
//     b128/b64 stores and b64/b32 reads); double-buffered, 1 barrier/plane
//   * W inner loop identical to the proven r5 code; loads in-loop (NO
//     register prefetch -- r1 showed the extra live set costs a wave tier)
//
// REVERT CUE: if WRITE_SIZE balloons (MBs+), the 128 cap spilled (r6
// signature) -> abandon the 128-tier, return to r0 structure.
// DO NOT: re-add hoisted prefetch registers (r1: -19%).
// ---------------------------------------------------------------------------

#define WSZ 11
#define DIN 192
#define DOUTS 182
#define TH 16              // tile height (output rows, y)
#define TWD 32             // tile width  (output cols, x)
#define IHR 26             // input rows per plane tile (TH + 10)
#define ZCH 24             // output planes per chunk
#define ZIN 34             // input planes per chunk (ZCH + 10)
#define NTX 6              // x tiles (6*32 = 192)
#define NTY 12             // y tiles (12*16 = 192)
#define ZC 8               // z-chunks (8*24 = 192)
#define NBLK (NTX*NTY*2*ZC)  // 1152
#define LSTR (TWD+2)       // LDS row stride 34: even (8B-align) + conflict-free
static constexpr double SOUT = 2.0 * 182.0 * 182.0 * 182.0;  // 12,057,136

typedef float v2f __attribute__((ext_vector_type(2)));

struct G11 { float g[WSZ]; };

__device__ __forceinline__ v2f pkfma(float g, v2f v, v2f a) {
    v2f gg = {g, g};
    return __builtin_elementwise_fma(gg, v, a);
}

__device__ __forceinline__ unsigned int enc_f(float f) {
    unsigned int u = __float_as_uint(f);
    return (u & 0x80000000u) ? ~u : (u | 0x80000000u);
}
__device__ __forceinline__ float dec_f(unsigned int u) {
    return (u & 0x80000000u) ? __uint_as_float(u & 0x7FFFFFFFu) : __uint_as_float(~u);
}

// ---------------------------------------------------------------------------
__global__ void k_init(unsigned int* mm, double* sum) {
    sum[0] = 0.0;
    mm[0] = 0u;           // encoded -inf (max accumulator)
    mm[1] = 0xFFFFFFFFu;  // encoded +inf (min accumulator)
}

// ---------------------------------------------------------------------------
__global__ __launch_bounds__(256) void k_minmax(const float4* __restrict__ img1,
                                                int n4, unsigned int* mm) {
    float mx = -1e30f, mn = 1e30f;
    for (int i = blockIdx.x * blockDim.x + threadIdx.x; i < n4;
         i += gridDim.x * blockDim.x) {
        float4 v = img1[i];
        mx = fmaxf(mx, fmaxf(fmaxf(v.x, v.y), fmaxf(v.z, v.w)));
        mn = fminf(mn, fminf(fminf(v.x, v.y), fminf(v.z, v.w)));
    }
    #pragma unroll
    for (int o = 32; o; o >>= 1) {
        mx = fmaxf(mx, __shfl_down(mx, o));
        mn = fminf(mn, __shfl_down(mn, o));
    }
    __shared__ float smx[4], smn[4];
    int lane = threadIdx.x & 63, wv = threadIdx.x >> 6;
    if (lane == 0) { smx[wv] = mx; smn[wv] = mn; }
    __syncthreads();
    if (threadIdx.x == 0) {
        #pragma unroll
        for (int i = 1; i < 4; i++) { mx = fmaxf(mx, smx[i]); mn = fminf(mn, smn[i]); }
        atomicMax(&mm[0], enc_f(mx));
        atomicMin(&mm[1], enc_f(mn));
    }
}

// ---------------------------------------------------------------------------
// 512 threads, tile 32(x) x 16(y), thread owns ONE output column.
// launch_bounds(512,4): reg cap 128 -> 4 waves/SIMD (2 blocks/CU).
__global__ __launch_bounds__(512, 4) void k_ssim(const float* __restrict__ img1,
                                                 const float* __restrict__ img2,
                                                 const unsigned int* __restrict__ mm,
                                                 double* __restrict__ sum, G11 gw) {
    // Channel-interleaved, double-buffered W-conv planes (35.4 KB total):
    //   twsA[h][x] = (mu1, mu2)   twsB[h][x] = (E11, E22)   twsC[h][x] = E12
    __shared__ float twsA[2][IHR][LSTR][2];
    __shared__ float twsB[2][IHR][LSTR][2];
    __shared__ float twsC[2][IHR][LSTR];
    __shared__ float sred[8];

    int b   = blockIdx.x;
    int twi = b % NTX;
    int thi = (b / NTX) % NTY;
    int rest = b / (NTX * NTY);
    int tc  = rest % ZC;
    int n   = rest / ZC;                 // batch 0..1
    int ow0 = twi * TWD, oh0 = thi * TH, od0 = tc * ZCH;
    int tid = threadIdx.x;
    int y = tid >> 5, x = tid & 31;      // thread owns output (y, x)

    // SSIM constants (L from img1 min/max, computed by k_minmax)
    float maxv = dec_f(mm[0]);
    float minv = dec_f(mm[1]);
    float max_val = (maxv > 128.0f) ? 255.0f : 1.0f;
    float min_val = (minv < -0.5f) ? -1.0f : 0.0f;
    float L  = max_val - min_val;
    float C1 = 0.01f * L; C1 *= C1;
    float C2 = 0.03f * L; C2 *= C2;

    bool vout = (oh0 + y < DOUTS) && (ow0 + x < DOUTS);

    // W-item geometry: 416 pair-items (row wh in [0,26), x-pair wxp in [0,16)),
    // one per thread for tid < 416. Clamped rows/cols feed only masked outputs.
    int wh  = tid >> 4, wxp = tid & 15;
    bool wact = (tid < IHR * 16);
    int hr = min(oh0 + wh, DIN - 1);
    int s  = min(ow0 + 2 * wxp, DIN - 12);   // even -> float2 loads 8B-aligned
    const float* wp1 = img1 + (size_t)n * DIN * DIN * DIN + (size_t)hr * DIN + s;
    const float* wp2 = img2 + (size_t)n * DIN * DIN * DIN + (size_t)hr * DIN + s;

    // D-conv packed shift pipeline: index j covers output zo = zi - j.
    // 55 floats of state: the whole point of the 1-output-per-thread layout.
    v2f accMu[WSZ], accE[WSZ];
    float acc12[WSZ];
    float local = 0.f;

    for (int zi = 0; zi < ZIN; zi++) {
        int d   = min(od0 + zi, DIN - 1);  // clamped planes feed only masked zo
        int buf = zi & 1;

        // ---- W phase (r5-proven inner loop): x-conv, (img1,img2) packed ----
        if (wact) {
            size_t zoff = (size_t)d * (DIN * DIN);
            const float2* p1 = (const float2*)(wp1 + zoff);
            const float2* p2 = (const float2*)(wp2 + zoff);
            v2f p[12];                               // lane-pair = (img1, img2)
            #pragma unroll
            for (int q = 0; q < 6; q++) {
                float2 f1 = p1[q];
                float2 f2 = p2[q];
                p[2*q]   = (v2f){f1.x, f2.x};
                p[2*q+1] = (v2f){f1.y, f2.y};
            }
            v2f amu[2] = {{0.f,0.f},{0.f,0.f}};      // (mu1, mu2) per output
            v2f asq[2] = {{0.f,0.f},{0.f,0.f}};      // (E11, E22) per output
            float a12[2] = {0.f, 0.f};               // E12 per output
            #pragma unroll
            for (int k = 0; k < WSZ; k++) {
                float g = gw.g[k];
                #pragma unroll
                for (int o = 0; o < 2; o++) {
                    v2f e = p[k + o];
                    v2f t = (v2f){g, g} * e;         // pk_mul
                    amu[o] += t;                     // pk_add
                    asq[o] = __builtin_elementwise_fma(t, e, asq[o]);  // pk_fma
                    a12[o] = fmaf(t.x, e.y, a12[o]); // cross term
                }
            }
            int xo = 2 * wxp;
            *(v2f*)&twsA[buf][wh][xo][0]     = amu[0];   // merges to b128
            *(v2f*)&twsA[buf][wh][xo + 1][0] = amu[1];
            *(v2f*)&twsB[buf][wh][xo][0]     = asq[0];
            *(v2f*)&twsB[buf][wh][xo + 1][0] = asq[1];
            *(v2f*)&twsC[buf][wh][xo]        = (v2f){a12[0], a12[1]};
        }
        __syncthreads();   // only barrier/plane (double-buffered tws)

        // ---- H phase: y-conv, channel-packed ds_read_b64 per (k) ----
        v2f mMu = {0.f, 0.f}, mE = {0.f, 0.f};
        float m12 = 0.f;
        #pragma unroll
        for (int k = 0; k < WSZ; k++) {
            float g = gw.g[k];
            mMu = pkfma(g, *(const v2f*)&twsA[buf][y + k][x][0], mMu);
            mE  = pkfma(g, *(const v2f*)&twsB[buf][y + k][x][0], mE);
            m12 = fmaf(g, twsC[buf][y + k][x], m12);
        }
        // No second barrier: W(zi+2) reuses this buffer only after every
        // wave passes barrier(zi+1)  [scheme proven correct in r1].

        // ---- D shift-FMA (channel-packed): acc[j] = g[j]*m + acc[j-1] ----
        #pragma unroll
        for (int j = WSZ - 1; j >= 1; j--) {
            accMu[j] = pkfma(gw.g[j], mMu, accMu[j-1]);
            accE[j]  = pkfma(gw.g[j], mE,  accE[j-1]);
            acc12[j] = fmaf(gw.g[j], m12, acc12[j-1]);
        }
        accMu[0] = (v2f){gw.g[0], gw.g[0]} * mMu;
        accE[0]  = (v2f){gw.g[0], gw.g[0]} * mE;
        acc12[0] = gw.g[0] * m12;

        // ---- SSIM for completed output plane zo = zi - 10 ----
        if (zi >= WSZ - 1) {
            int zo = od0 + zi - (WSZ - 1);
            if (zo < DOUTS && vout) {
                float mu1 = accMu[10].x, mu2 = accMu[10].y;
                float mu1s = mu1 * mu1, mu2s = mu2 * mu2, mu12 = mu1 * mu2;
                float s1  = accE[10].x - mu1s;
                float s2  = accE[10].y - mu2s;
                float s12 = acc12[10] - mu12;
                float v1  = 2.f * s12 + C2;
                float v2  = s1 + s2 + C2;
                float num = (2.f * mu12 + C1) * v1;
                float den = (mu1s + mu2s + C1) * v2;
                local += num / den;
            }
        }
    }

    // ---- block reduction (8 waves) -> one f64 atomic ----
    #pragma unroll
    for (int o = 32; o; o >>= 1) local += __shfl_down(local, o);
    if ((tid & 63) == 0) sred[tid >> 6] = local;
    __syncthreads();
    if (tid == 0) {
        float t = 0.f;
        #pragma unroll
        for (int i = 0; i < 8; i++) t += sred[i];
        atomicAdd(sum, (double)t);
    }
}

// ---------------------------------------------------------------------------
__global__ void k_final(const double* __restrict__ sum, float* __restrict__ out) {
    out[0] = (float)(sum[0] / SOUT);
}

// ---------------------------------------------------------------------------
extern "C" void kernel_launch(void* const* d_in, const int* in_sizes, int n_in,
                              void* d_out, int out_size, void* d_ws, size_t ws_size,
                              hipStream_t stream) {
    const float* img1 = (const float*)d_in[0];
    const float* img2 = (const float*)d_in[1];
    float* out = (float*)d_out;

    char* ws = (char*)d_ws;
    double*       sum = (double*)ws;              // 8 B
    unsigned int* mm  = (unsigned int*)(ws + 8);  // 8 B

    // Gaussian weights: f64 compute, normalize, cast to f32 (matches ref).
    G11 g;
    {
        double gd[WSZ], s = 0.0;
        for (int i = 0; i < WSZ; i++) {
            double d = (double)(i - WSZ / 2);
            gd[i] = std::exp(-(d * d) / (2.0 * 1.5 * 1.5));
            s += gd[i];
        }
        for (int i = 0; i < WSZ; i++) g.g[i] = (float)(gd[i] / s);
    }

    int n_img = 2 * DIN * DIN * DIN;  // 14,155,776

    k_init<<<1, 1, 0, stream>>>(mm, sum);
    k_minmax<<<2048, 256, 0, stream>>>((const float4*)img1, n_img / 4, mm);
    k_ssim<<<NBLK, 512, 0, stream>>>(img1, img2, mm, sum, g);
    k_final<<<1, 1, 0, stream>>>(sum, out);
}